// Round 2
// baseline (359.549 us; speedup 1.0000x reference)
//
#include <hip/hip_runtime.h>

// HamiltonianMetric: y[b] = u^T u, u = scatter(tanh(MLP(x))).
// R2: 16-batch blocks (2 blocks/CU), W3 permuted+padded to uT layout in prep
// (no decode, linear scatter), double-buffered W3 prefetch, nontemporal y.

typedef __bf16 bf16_t;
typedef bf16_t bf16x8 __attribute__((ext_vector_type(8)));
typedef float  f32x4  __attribute__((ext_vector_type(4)));

#define MFMA16(a, b, c) __builtin_amdgcn_mfma_f32_16x16x32_bf16((a), (b), (c), 0, 0, 0)

constexpr int SLOT = 4624;    // bytes per uT slot: >=4608, 16B-aligned, (SLOT/4)%32==4
constexpr int TP   = 2304;    // padded triangle length (rows padded to 8 elems)
constexpr int NT3  = TP / 16; // 144 stage-3 n-tiles

__device__ __forceinline__ float fast_tanh(float x) {
  float cx = fminf(fmaxf(x, -30.0f), 30.0f);
  float t  = __expf(2.0f * cx);
  return (t - 1.0f) * __builtin_amdgcn_rcpf(t + 1.0f);
}

__device__ __forceinline__ bf16x8 zsel(bf16x8 f, bool keep) {
  union { bf16x8 v; unsigned int u[4]; } x;
  x.v = f;
  unsigned m = keep ? 0xFFFFFFFFu : 0u;
#pragma unroll
  for (int p = 0; p < 4; ++p) x.u[p] &= m;
  return x.v;
}

// padded position p -> (j, k) of uT (row j has j+1 valid entries, padded to 8-mult)
__device__ __forceinline__ void decode_p(int p, int& j, int& k) {
  int cc = p >> 3, e = p & 7;
  int b = 0;
  while (b < 7 && cc >= 4 * (b + 1) * (b + 2)) ++b;
  int rl  = b + 1;
  int rem = cc - 4 * b * (b + 1);
  j = 8 * b + rem / rl;
  k = (rem % rl) * 8 + e;
}

// ws layout (bf16 unless noted):
//   [0,16384)        W1t [256 n][64 k]
//   [16384,81920)    W2t [256 n][256 k]
//   [81920,671744)   W3p [2304 p][256 k]   (permuted + zero-padded)
//   byte 1343488..   b3p [2304] f32        (permuted + zero-padded)
__global__ void prep_kernel(const float* __restrict__ W1, const float* __restrict__ W2,
                            const float* __restrict__ W3, const float* __restrict__ b3,
                            char* __restrict__ wsb) {
  int tid = blockIdx.x * 512 + threadIdx.x;
  bf16_t* ws = (bf16_t*)wsb;
  if (tid < 16384) {
    int n = tid >> 6, k = tid & 63;
    ws[tid] = (bf16_t)W1[k * 256 + n];
  } else if (tid < 81920) {
    int m = tid - 16384;
    int n = m >> 8, k = m & 255;
    ws[tid] = (bf16_t)W2[k * 256 + n];
  } else if (tid < 671744) {
    int m = tid - 81920;
    int p = m >> 8, kcol = m & 255;
    int j, k;
    decode_p(p, j, k);
    float v = 0.f;
    if (k <= j) {
      int n_ref = (k == j) ? j : (64 + k * 63 - (k * (k - 1)) / 2 + j - k - 1);
      v = W3[kcol * 2080 + n_ref];
    }
    ws[tid] = (bf16_t)v;
  } else if (tid < 674048) {
    int p = tid - 671744;
    int j, k;
    decode_p(p, j, k);
    float v = 0.f;
    if (k <= j) {
      int n_ref = (k == j) ? j : (64 + k * 63 - (k * (k - 1)) / 2 + j - k - 1);
      v = b3[n_ref];
    }
    ((float*)(wsb + 1343488))[p] = v;
  }
}

__global__ void __launch_bounds__(512, 4)
hm_kernel(const float* __restrict__ x, const float* __restrict__ b1,
          const float* __restrict__ b2, const char* __restrict__ wsb,
          float* __restrict__ out) {
  extern __shared__ char smem[];  // 73984 B: 16 uT slots of SLOT bytes
  const int tid  = threadIdx.x;
  const int w    = tid >> 6;   // wave 0..7
  const int lane = tid & 63;
  const int g    = lane >> 4;  // 0..3
  const int c    = lane & 15;  // 0..15
  const int blk  = blockIdx.x;

  const bf16_t* W1t = (const bf16_t*)wsb;
  const bf16_t* W2t = W1t + 16384;
  const bf16_t* W3p = W1t + 81920;
  const float*  b3p = (const float*)(wsb + 1343488);

  char* xs  = smem;          // [16][64]  bf16, stride 128B, row-XOR swz
  char* h1s = smem + 4096;   // [16][256] bf16, stride 512B, swz
  char* h2s = smem + 16384;  // [16][256] bf16, stride 512B, swz

  // ---- load x tile: 16 rows x 64 f32 -> bf16 LDS ----
  if (tid < 256) {
    f32x4 v = *(const f32x4*)(x + (size_t)blk * 1024 + tid * 4);
    int row = tid >> 4, col = (tid & 15) * 4;
    union { bf16_t b[4]; unsigned long long u; } pk;
    pk.b[0] = (bf16_t)v[0]; pk.b[1] = (bf16_t)v[1];
    pk.b[2] = (bf16_t)v[2]; pk.b[3] = (bf16_t)v[3];
    *(unsigned long long*)(xs + ((row * 128 + col * 2) ^ ((row & 7) << 4))) = pk.u;
  }
  __syncthreads();

  // ---- stage 1: h1 = tanh(x @ W1 + b1), M=16, N=256 (2 n-tiles/wave) ----
  {
    bf16x8 a0 = *(const bf16x8*)(xs + ((c * 128 + g * 16) ^ ((c & 7) << 4)));
    bf16x8 a1 = *(const bf16x8*)(xs + ((c * 128 + 64 + g * 16) ^ ((c & 7) << 4)));
#pragma unroll
    for (int ni = 0; ni < 2; ++ni) {
      int n = (w * 2 + ni) * 16 + c;
      bf16x8 bw0 = *(const bf16x8*)(W1t + n * 64 + g * 8);
      bf16x8 bw1 = *(const bf16x8*)(W1t + n * 64 + 32 + g * 8);
      f32x4 acc = {0.f, 0.f, 0.f, 0.f};
      acc = MFMA16(a0, bw0, acc);
      acc = MFMA16(a1, bw1, acc);
      float bias = b1[n];
#pragma unroll
      for (int r = 0; r < 4; ++r) {
        int row = g * 4 + r;
        float v = fast_tanh(acc[r] + bias);
        *(bf16_t*)(h1s + ((row * 512 + n * 2) ^ ((row & 7) << 4))) = (bf16_t)v;
      }
    }
  }
  __syncthreads();

  // ---- stage 2: h2 = tanh(h1 @ W2 + b2), K=256 ----
#pragma unroll
  for (int ni = 0; ni < 2; ++ni) {
    int n = (w * 2 + ni) * 16 + c;
    f32x4 acc0 = {0.f, 0.f, 0.f, 0.f}, acc1 = {0.f, 0.f, 0.f, 0.f};
#pragma unroll
    for (int kk = 0; kk < 8; kk += 2) {
      bf16x8 a0 = *(const bf16x8*)(h1s + ((c * 512 + kk * 64 + g * 16) ^ ((c & 7) << 4)));
      bf16x8 a1 = *(const bf16x8*)(h1s + ((c * 512 + (kk + 1) * 64 + g * 16) ^ ((c & 7) << 4)));
      bf16x8 bw0 = *(const bf16x8*)(W2t + n * 256 + kk * 32 + g * 8);
      bf16x8 bw1 = *(const bf16x8*)(W2t + n * 256 + (kk + 1) * 32 + g * 8);
      acc0 = MFMA16(a0, bw0, acc0);
      acc1 = MFMA16(a1, bw1, acc1);
    }
    f32x4 acc = acc0 + acc1;
    float bias = b2[n];
#pragma unroll
    for (int r = 0; r < 4; ++r) {
      int row = g * 4 + r;
      float v = fast_tanh(acc[r] + bias);
      *(bf16_t*)(h2s + ((row * 512 + n * 2) ^ ((row & 7) << 4))) = (bf16_t)v;
    }
  }
  __syncthreads();

  // ---- hoist h2 A-fragments to registers, then arena becomes uT slots ----
  bf16x8 h2f[8];
#pragma unroll
  for (int kk = 0; kk < 8; ++kk)
    h2f[kk] = *(const bf16x8*)(h2s + ((c * 512 + kk * 64 + g * 16) ^ ((c & 7) << 4)));
  __syncthreads();

  // ---- stage 3: t = tanh(h2 @ W3p + b3p) -> linear write into 16 uT slots ----
  // double-buffered W3 prefetch; 18 tiles per wave (144 / 8), exact.
  {
    bf16x8 bwA[8], bwB[8];
    float biasA, biasB;
    auto LOAD3 = [&](bf16x8* bw, float& bias, int nt) {
      int p = nt * 16 + c;
#pragma unroll
      for (int kk = 0; kk < 8; ++kk)
        bw[kk] = *(const bf16x8*)(W3p + p * 256 + kk * 32 + g * 8);
      bias = b3p[p];
    };
    auto COMP3 = [&](const bf16x8* bw, float bias, int nt) {
      int p = nt * 16 + c;
      f32x4 acc0 = {0.f, 0.f, 0.f, 0.f}, acc1 = {0.f, 0.f, 0.f, 0.f};
#pragma unroll
      for (int kk = 0; kk < 8; kk += 2) {
        acc0 = MFMA16(h2f[kk], bw[kk], acc0);
        acc1 = MFMA16(h2f[kk + 1], bw[kk + 1], acc1);
      }
      f32x4 acc = acc0 + acc1;
#pragma unroll
      for (int r = 0; r < 4; ++r) {
        float v = fast_tanh(acc[r] + bias);
        *(bf16_t*)(smem + (g * 4 + r) * SLOT + p * 2) = (bf16_t)v;
      }
    };
    LOAD3(bwA, biasA, w);
#pragma unroll 1
    for (int it = 0; it < 18; it += 2) {
      int ntA = w + it * 8;
      LOAD3(bwB, biasB, ntA + 8);
      COMP3(bwA, biasA, ntA);
      if (it + 2 < 18) LOAD3(bwA, biasA, ntA + 16);
      COMP3(bwB, biasB, ntA + 8);
    }
  }
  __syncthreads();

  // ---- stage 4: y = Gram(uT) per batch; 2 batches per wave ----
#pragma unroll
  for (int bi = 0; bi < 2; ++bi) {
    const char* slot = smem + (w * 2 + bi) * SLOT;
    // row offset in padded layout: Q=j>>3, s=j&7 -> 16*(4Q(Q+1)+s(Q+1)) bytes
    bf16x8 f0, f1, f2, f3, f2b, f3b;
#pragma unroll
    for (int ti = 0; ti < 4; ++ti) {
      int j = ti * 16 + c;
      int Q = j >> 3, s = j & 7;
      int ro = 16 * (4 * Q * (Q + 1) + s * (Q + 1));
      int kb0 = g * 8;
      bf16x8 fa = *(const bf16x8*)(slot + ro + kb0 * 2);
      fa = zsel(fa, kb0 <= j);
      if (ti == 0) f0 = fa;
      if (ti == 1) f1 = fa;
      if (ti == 2) f2 = fa;
      if (ti == 3) f3 = fa;
      if (ti >= 2) {
        int kb1 = 32 + g * 8;
        bf16x8 fb = *(const bf16x8*)(slot + ro + kb1 * 2);
        fb = zsel(fb, kb1 <= j);
        if (ti == 2) f2b = fb;
        else         f3b = fb;
      }
    }
    bf16x8 fA[4] = {f0, f1, f2, f3};
    f32x4 acc[4][4];
#pragma unroll
    for (int ti = 0; ti < 4; ++ti)
#pragma unroll
      for (int tj = 0; tj < 4; ++tj) {
        f32x4 z = {0.f, 0.f, 0.f, 0.f};
        acc[ti][tj] = MFMA16(fA[ti], fA[tj], z);
      }
    acc[2][2] = MFMA16(f2b, f2b, acc[2][2]);
    acc[2][3] = MFMA16(f2b, f3b, acc[2][3]);
    acc[3][2] = MFMA16(f3b, f2b, acc[3][2]);
    acc[3][3] = MFMA16(f3b, f3b, acc[3][3]);

    // direct nontemporal stores: each instr covers 4 full 64B segments
    float* yb = out + (size_t)(blk * 16 + w * 2 + bi) * 4096;
#pragma unroll
    for (int ti = 0; ti < 4; ++ti)
#pragma unroll
      for (int tj = 0; tj < 4; ++tj)
#pragma unroll
        for (int r = 0; r < 4; ++r)
          __builtin_nontemporal_store(acc[ti][tj][r],
                                      yb + (ti * 16 + g * 4 + r) * 64 + tj * 16 + c);
  }
}

extern "C" void kernel_launch(void* const* d_in, const int* in_sizes, int n_in,
                              void* d_out, int out_size, void* d_ws, size_t ws_size,
                              hipStream_t stream) {
  (void)in_sizes; (void)n_in; (void)out_size; (void)ws_size;
  const float* x  = (const float*)d_in[0];
  const float* W1 = (const float*)d_in[1];
  const float* b1 = (const float*)d_in[2];
  const float* W2 = (const float*)d_in[3];
  const float* b2 = (const float*)d_in[4];
  const float* W3 = (const float*)d_in[5];
  const float* b3 = (const float*)d_in[6];
  char* wsb = (char*)d_ws;   // needs 1,352,704 B
  float* out = (float*)d_out;

  prep_kernel<<<1317, 512, 0, stream>>>(W1, W2, W3, b3, wsb);

  hipFuncSetAttribute((const void*)hm_kernel,
                      hipFuncAttributeMaxDynamicSharedMemorySize, 73984);
  hm_kernel<<<2048, 512, 73984, stream>>>(x, b1, b2, wsb, out);
}